// Round 3
// baseline (133.373 us; speedup 1.0000x reference)
//
#include <hip/hip_runtime.h>

// Submanifold sparse conv — 3 dispatches.
//   1. hipMemsetAsync grid+bitmap to 0
//   2. build_grid: atomicMax(grid[key], n-i) + atomicOr(bitmap bit)
//   3. conv: block = 64 points, block-local rulebook in LDS:
//        P0 stage: pos rows -> LDS (coalesced); zero s_acc (replaces old P2's
//            init-by-center-write).
//        P1a probe: bitmap-only probes (L2-resident 275 KB); hits append
//            (pl<<22|key) to per-offset LDS lists. No grid reads here.
//        P1b resolve: all ~144 grid lookups (80 neighbors + 64 centers) in ONE
//            parallel batch; entries rewritten to (pl<<17|j); centers to s_rep.
//        P3a center drain: o=13 list (s_rep, 64 entries) split over all 8
//            half-waves, 2-deep pipelined. R2 post-mortem: old P2 was a
//            ~7k-cycle serial chain (8 un-unrolled dependent iterations).
//        P3b neighbor drain: wave w handles offsets o=w,w+4,...; W[o] column
//            loaded once per (block,offset); 2-deep pipelined.
//        BOTH drains use an asm "memory" fence between the 16 float4 loads and
//            the FMA block — R2 showed hipcc re-interleaves loads into the FMA
//            stream to save VGPRs (VGPR stayed 40), killing MLP. The fence
//            forces all 16 loads issued first (VGPR ~120 expected).
//        P4 write-out: coalesced plain stores.

#define GRID_B 130
#define GRID_CELLS 2197000      // 130^3
#define BM_WORDS 68704          // ceil(130^3 / 32) = 68657, padded so w+1 reads stay in-bounds
#define C 32
#define NTHR 256
#define PTS 64                  // points per block
#define CAP 24                  // per-offset list cap (Binom(64,0.048); P(>24) ~ 1e-13)

__global__ void build_grid_kernel(const int* __restrict__ pos,
                                  int* __restrict__ grid,
                                  unsigned int* __restrict__ bm, int n) {
    int i = blockIdx.x * blockDim.x + threadIdx.x;
    if (i >= n) return;
    int x = pos[3 * i + 0] + 1;
    int y = pos[3 * i + 1] + 1;
    int z = pos[3 * i + 2] + 1;
    int key = (x * GRID_B + y) * GRID_B + z;
    atomicMax(&grid[key], n - i);
    atomicOr(&bm[key >> 5], 1u << (key & 31));
}

__global__ __launch_bounds__(NTHR)
void conv_kernel(const float* __restrict__ feat,
                 const int* __restrict__ pos,
                 const float* __restrict__ w,
                 const int* __restrict__ grid,
                 const unsigned int* __restrict__ bm,
                 float* __restrict__ out, int n) {
    __shared__ int   s_cnt[27];
    __shared__ int   s_list[27][CAP];     // P1a: (pl<<22)|key ; P1b: (pl<<17)|j
    __shared__ int   s_rep[PTS];          // P1a: center key ; P1b: center j
    __shared__ int   s_pos[PTS * 3];      // staged positions
    __shared__ float s_acc[PTS][C];       // 8 KB accumulator tile

    const int tid = threadIdx.x;
    const int pt_base = blockIdx.x * PTS;

    if (tid < 27) s_cnt[tid] = 0;
    // ---- P0: stage positions (coalesced) + zero the accumulator tile ----
    for (int u = tid; u < PTS * 3; u += NTHR) {
        int g = pt_base * 3 + u;
        if (g < n * 3) s_pos[u] = pos[g];
    }
    {
        float* a = &s_acc[0][0];
        for (int u = tid; u < PTS * C; u += NTHR) a[u] = 0.0f;
    }
    __syncthreads();

    // ---- P1a: 64 pts x 9 (dx,dy) columns; bitmap gives the z-triple ----
    for (int t = tid; t < PTS * 9; t += NTHR) {
        int pl = t / 9;                  // const-div -> magic mul
        int xy = t - pl * 9;
        if (pt_base + pl < n) {
            int dx = xy / 3;             // 0..2
            int dy = xy - dx * 3;        // 0..2
            int x0 = s_pos[pl * 3 + 0] + dx;         // (x+1) + (dx-1)
            int y0 = s_pos[pl * 3 + 1] + dy;
            // key of (x0, y0, z-1): z base = pos.z (+1 shift, -1 offset)
            int k0 = (x0 * GRID_B + y0) * GRID_B + s_pos[pl * 3 + 2];
            unsigned int w0 = bm[(k0 >> 5)];
            unsigned int w1 = bm[(k0 >> 5) + 1];     // L2-hot, usually same line
            unsigned int bits =
                (unsigned int)((((unsigned long long)w1 << 32) | w0) >> (k0 & 31)) & 7u;
            int obase = xy * 3;          // o = (dx*3+dy)*3 + oz
            if (xy == 4) {
                s_rep[pl] = k0 + 1;      // center key; resolved in P1b
                bits &= 5u;
            }
            while (bits) {
                int oz = __ffs(bits) - 1;
                bits &= bits - 1;
                int slot = atomicAdd(&s_cnt[obase + oz], 1);
                if (slot < CAP) s_list[obase + oz][slot] = (pl << 22) | (k0 + oz);
            }
        }
    }
    __syncthreads();

    // ---- P1b: resolve all grid lookups in one parallel batch ----
    for (int t = tid; t < 27 * CAP + PTS; t += NTHR) {
        if (t < 27 * CAP) {
            int o = t / CAP;             // const-div -> magic mul
            int slot = t - o * CAP;
            if (o != 13 && slot < min(s_cnt[o], CAP)) {
                unsigned int e = (unsigned int)s_list[o][slot];
                int v = grid[e & 0x3FFFFF];
                s_list[o][slot] = (int)((e >> 22) << 17) | (n - v);
            }
        } else {
            int pl = t - 27 * CAP;
            if (pt_base + pl < n)
                s_rep[pl] = n - grid[s_rep[pl]];   // center j
        }
    }
    __syncthreads();

    // ---- P3a: center drain (o=13), all 8 half-waves, 2-deep pipelined ----
    {
        const int hw8 = tid >> 5;         // half-wave id 0..7
        const int cout = tid & 31;
        const int cnt13 = min(PTS, n - pt_base);   // >0 always
        float wreg[32];
        #pragma unroll
        for (int c = 0; c < 32; ++c) wreg[c] = w[13 * 1024 + c * 32 + cout];
        for (int e = hw8; e < cnt13; e += 16) {
            int eb = e + 8;
            int hb = (eb < cnt13);
            int ja = s_rep[e];                     // LDS same-addr broadcast
            int jb = hb ? s_rep[eb] : ja;
            const float4* __restrict__ A = (const float4*)(feat + (size_t)ja * C);
            const float4* __restrict__ Bp = (const float4*)(feat + (size_t)jb * C);
            float4 av[8], bv[8];
            #pragma unroll
            for (int k = 0; k < 8; ++k) av[k] = A[k];
            #pragma unroll
            for (int k = 0; k < 8; ++k) bv[k] = Bp[k];
            asm volatile("" ::: "memory");         // fence: all 16 loads issued first
            float acca = 0.0f, accb = 0.0f;
            #pragma unroll
            for (int k = 0; k < 8; ++k) {
                acca = fmaf(av[k].x, wreg[4 * k + 0], acca);
                acca = fmaf(av[k].y, wreg[4 * k + 1], acca);
                acca = fmaf(av[k].z, wreg[4 * k + 2], acca);
                acca = fmaf(av[k].w, wreg[4 * k + 3], acca);
                accb = fmaf(bv[k].x, wreg[4 * k + 0], accb);
                accb = fmaf(bv[k].y, wreg[4 * k + 1], accb);
                accb = fmaf(bv[k].z, wreg[4 * k + 2], accb);
                accb = fmaf(bv[k].w, wreg[4 * k + 3], accb);
            }
            atomicAdd(&s_acc[e][cout], acca);      // ds_add_f32, banks clean
            if (hb) atomicAdd(&s_acc[eb][cout], accb);
        }
    }
    // no barrier: P3a and P3b both accumulate via ds_add

    // ---- P3b: neighbor drain; W[o] column amortized per (block,offset) ----
    {
        const int wv = tid >> 6;          // wave 0..3
        const int lane = tid & 63;
        const int cout = lane & 31;
        const int half = lane >> 5;
        for (int o = wv; o < 27; o += 4) {
            if (o == 13) continue;
            int cnt = min(s_cnt[o], CAP);
            if (cnt == 0) continue;
            float wreg[32];
            #pragma unroll
            for (int c = 0; c < 32; ++c) wreg[c] = w[o * 1024 + c * 32 + cout];
            for (int e0 = half * 2; e0 < cnt; e0 += 4) {   // 2 entries per half-wave iter
                int pk0 = s_list[o][e0];
                int h1 = (e0 + 1 < cnt);
                int pk1 = h1 ? s_list[o][e0 + 1] : pk0;
                const float4* __restrict__ A = (const float4*)(feat + (size_t)(pk0 & 0x1FFFF) * C);
                const float4* __restrict__ Bp = (const float4*)(feat + (size_t)(pk1 & 0x1FFFF) * C);
                float4 av[8], bv[8];
                #pragma unroll
                for (int k = 0; k < 8; ++k) av[k] = A[k];
                #pragma unroll
                for (int k = 0; k < 8; ++k) bv[k] = Bp[k];
                asm volatile("" ::: "memory");     // fence: all 16 loads issued first
                float acca = 0.0f, accb = 0.0f;
                #pragma unroll
                for (int k = 0; k < 8; ++k) {
                    acca = fmaf(av[k].x, wreg[4 * k + 0], acca);
                    acca = fmaf(av[k].y, wreg[4 * k + 1], acca);
                    acca = fmaf(av[k].z, wreg[4 * k + 2], acca);
                    acca = fmaf(av[k].w, wreg[4 * k + 3], acca);
                    accb = fmaf(bv[k].x, wreg[4 * k + 0], accb);
                    accb = fmaf(bv[k].y, wreg[4 * k + 1], accb);
                    accb = fmaf(bv[k].z, wreg[4 * k + 2], accb);
                    accb = fmaf(bv[k].w, wreg[4 * k + 3], accb);
                }
                atomicAdd(&s_acc[pk0 >> 17][cout], acca);
                if (h1) atomicAdd(&s_acc[pk1 >> 17][cout], accb);
            }
        }
    }
    __syncthreads();

    // ---- P4: coalesced write-out (block owns its 64 points exclusively) ----
    {
        const int base = pt_base * C;
        const int lim = n * C - base;                  // last block: exactly 1024
        for (int u = tid; u < PTS * C && u < lim; u += NTHR)
            out[base + u] = s_acc[u >> 5][u & 31];
    }
}

extern "C" void kernel_launch(void* const* d_in, const int* in_sizes, int n_in,
                              void* d_out, int out_size, void* d_ws, size_t ws_size,
                              hipStream_t stream) {
    const float* features = (const float*)d_in[0];
    const int*   positions = (const int*)d_in[1];
    const float* weight = (const float*)d_in[2];
    float* out = (float*)d_out;
    const int n = in_sizes[0] / C;       // 100000

    int* grid = (int*)d_ws;
    unsigned int* bm = (unsigned int*)(grid + GRID_CELLS);
    hipMemsetAsync(d_ws, 0, (size_t)(GRID_CELLS + BM_WORDS) * sizeof(int), stream);

    build_grid_kernel<<<(n + 255) / 256, 256, 0, stream>>>(positions, grid, bm, n);

    conv_kernel<<<(n + PTS - 1) / PTS, NTHR, 0, stream>>>(features, positions, weight,
                                                          grid, bm, out, n);
}

// Round 5
// 128.244 us; speedup vs baseline: 1.0400x; 1.0400x over previous
//
#include <hip/hip_runtime.h>

// Submanifold sparse conv — 3 dispatches.
//   1. hipMemsetAsync grid+bitmap to 0
//   2. build_grid: atomicMax(grid[key], n-i) + atomicOr(bitmap bit)
//   3. conv: block = 64 points. R3 post-mortem: hipcc pins VGPR at 40 and
//      serializes gather waits (one waitcnt per 128B row, ~600-900cy each,
//      ~35us/block critical path) — source-level pipelining/fences CANNOT fix
//      it. R4/R5: replace all per-entry global gathers with async DMA
//      global_load_lds (vmcnt-counted, no VGPRs -> scheduler can't sink it):
//        P0  stage pos -> LDS
//        P1a bitmap-only probes (L2-resident 275 KB) -> per-offset lists
//        scan wave0 prefix-sums counts -> flat row segments (centers f=pl,
//             neighbors from f=64)
//        P1b resolve grid lookups in one parallel batch -> s_jidx[f] = j
//        P1c DMA-gather: ONE global_load_lds per 8 rows (lane l reads 16B of
//             row l>>3 from feat[j]; HW writes LDS base+lane*16). ~18 instrs
//             per block, ONE vmcnt(0) drain. This is the lever.
//        P3a center drain: row f=pl from LDS (same-addr broadcast, conflict-
//             free), plain-store init of s_acc
//        P3b neighbor drain: wave per offset stride 4, W[o] column amortized,
//             rows from LDS, ds_add_f32 into s_acc
//        P4  coalesced write-out
//      R5 hardening vs R4 (container died, no counters): __align__(16) on the
//      DMA-target LDS arrays (global_load_lds_dwordx4 writes base+lane*16; a
//      4B-aligned base can fault the memory pipe), and "memory" clobber on the
//      vmcnt(0) so LDS reads can't hoist above the drain.

#define GRID_B 130
#define GRID_CELLS 2197000      // 130^3
#define BM_WORDS 68704          // ceil(130^3/32)=68657, padded for w+1 reads
#define C 32
#define NTHR 256
#define PTS 64                  // points per block
#define CAP 24                  // per-offset list cap (P(cnt>24) ~ 1e-13)
#define ROWS_CAP 192            // flat gathered-row cap (mean 141, +5.7sigma)

__global__ void build_grid_kernel(const int* __restrict__ pos,
                                  int* __restrict__ grid,
                                  unsigned int* __restrict__ bm, int n) {
    int i = blockIdx.x * blockDim.x + threadIdx.x;
    if (i >= n) return;
    int x = pos[3 * i + 0] + 1;
    int y = pos[3 * i + 1] + 1;
    int z = pos[3 * i + 2] + 1;
    int key = (x * GRID_B + y) * GRID_B + z;
    atomicMax(&grid[key], n - i);
    atomicOr(&bm[key >> 5], 1u << (key & 31));
}

__global__ __launch_bounds__(NTHR)
void conv_kernel(const float* __restrict__ feat,
                 const int* __restrict__ pos,
                 const float* __restrict__ w,
                 const int* __restrict__ grid,
                 const unsigned int* __restrict__ bm,
                 float* __restrict__ out, int n) {
    __shared__ int   s_cnt[27];
    __shared__ int   s_seg[27];           // flat row segment start per offset
    __shared__ int   s_total;             // total gathered rows (incl 64 centers)
    __shared__ int   s_list[27][CAP];     // (pl<<22)|key
    __shared__ int   s_rep[PTS];          // center key
    __shared__ int   s_jidx[ROWS_CAP];    // resolved feature row index per flat slot
    __shared__ int   s_pos[PTS * 3];
    __shared__ __align__(16) float s_rows[ROWS_CAP][C]; // 24 KB DMA-gathered rows
    __shared__ __align__(16) float s_acc[PTS][C];       // 8 KB accumulator tile

    const int tid = threadIdx.x;
    const int pt_base = blockIdx.x * PTS;

    if (tid < 27) s_cnt[tid] = 0;
    // ---- P0: stage positions (coalesced) ----
    for (int u = tid; u < PTS * 3; u += NTHR) {
        int g = pt_base * 3 + u;
        if (g < n * 3) s_pos[u] = pos[g];
    }
    __syncthreads();

    // ---- P1a: 64 pts x 9 (dx,dy) columns; bitmap gives the z-triple ----
    for (int t = tid; t < PTS * 9; t += NTHR) {
        int pl = t / 9;
        int xy = t - pl * 9;
        if (pt_base + pl < n) {
            int dx = xy / 3;
            int dy = xy - dx * 3;
            int x0 = s_pos[pl * 3 + 0] + dx;
            int y0 = s_pos[pl * 3 + 1] + dy;
            int k0 = (x0 * GRID_B + y0) * GRID_B + s_pos[pl * 3 + 2];   // z-1 key
            unsigned int w0 = bm[(k0 >> 5)];
            unsigned int w1 = bm[(k0 >> 5) + 1];
            unsigned int bits =
                (unsigned int)((((unsigned long long)w1 << 32) | w0) >> (k0 & 31)) & 7u;
            int obase = xy * 3;
            if (xy == 4) {
                s_rep[pl] = k0 + 1;      // center key; resolved in P1b
                bits &= 5u;
            }
            while (bits) {
                int oz = __ffs(bits) - 1;
                bits &= bits - 1;
                int slot = atomicAdd(&s_cnt[obase + oz], 1);
                if (slot < CAP) s_list[obase + oz][slot] = (pl << 22) | (k0 + oz);
            }
        }
    }
    __syncthreads();

    // ---- scan: wave0 prefix-sums counts into flat segments ----
    if (tid < 64) {
        int o = tid;
        int c = (o < 27 && o != 13) ? min(s_cnt[o], CAP) : 0;
        int x = c;
        #pragma unroll
        for (int d = 1; d < 32; d <<= 1) {
            int y = __shfl_up(x, d, 64);
            if (tid >= d) x += y;
        }
        if (o < 27) s_seg[o] = PTS + x - c;   // exclusive start, centers occupy [0,64)
        if (o == 26) s_total = PTS + x;
    }
    __syncthreads();

    // ---- P1b: resolve all grid lookups in one parallel batch -> s_jidx ----
    for (int t = tid; t < 27 * CAP + PTS; t += NTHR) {
        if (t < 27 * CAP) {
            int o = t / CAP;
            int slot = t - o * CAP;
            if (o != 13 && slot < min(s_cnt[o], CAP)) {
                int f = s_seg[o] + slot;
                if (f < ROWS_CAP)
                    s_jidx[f] = n - grid[s_list[o][slot] & 0x3FFFFF];
            }
        } else {
            int pl = t - 27 * CAP;
            s_jidx[pl] = (pt_base + pl < n) ? (n - grid[s_rep[pl]]) : 0;
        }
    }
    __syncthreads();

    // ---- P1c: DMA-gather all rows into s_rows (the lever) ----
    {
        int totc = min(s_total, ROWS_CAP);
        int lane = tid & 63, wv = tid >> 6;
        int nI = (totc + 7) >> 3;             // 8 rows per instruction
        for (int i = wv; i < nI; i += 4) {
            int f = (i << 3) + (lane >> 3);
            int j = s_jidx[min(f, totc - 1)];         // clamped dup for tail lanes
            const float* g = feat + (size_t)j * C + ((lane & 7) << 2);
            __builtin_amdgcn_global_load_lds(
                (const __attribute__((address_space(1))) unsigned int*)g,
                (__attribute__((address_space(3))) unsigned int*)(&s_rows[i << 3][0]),
                16, 0, 0);                    // HW: LDS base + lane*16
        }
    }
    asm volatile("s_waitcnt vmcnt(0)" ::: "memory");
    __syncthreads();

    // ---- P3a: center drain; row f=pl; plain-store init of s_acc ----
    {
        const int hw8 = tid >> 5;             // half-wave 0..7
        const int cout = tid & 31;
        const int cnt13 = min(PTS, n - pt_base);
        float wreg[32];
        #pragma unroll
        for (int c = 0; c < 32; ++c) wreg[c] = w[13 * 1024 + c * 32 + cout];
        for (int e = hw8; e < cnt13; e += 8) {
            const float4* R = (const float4*)(&s_rows[e][0]);   // broadcast reads
            float acc = 0.0f;
            #pragma unroll
            for (int k = 0; k < 8; ++k) {
                float4 rv = R[k];
                acc = fmaf(rv.x, wreg[4 * k + 0], acc);
                acc = fmaf(rv.y, wreg[4 * k + 1], acc);
                acc = fmaf(rv.z, wreg[4 * k + 2], acc);
                acc = fmaf(rv.w, wreg[4 * k + 3], acc);
            }
            s_acc[e][cout] = acc;
        }
    }
    __syncthreads();

    // ---- P3b: neighbor drain; W[o] column amortized per (block,offset) ----
    {
        const int wv = tid >> 6;
        const int lane = tid & 63;
        const int cout = lane & 31;
        const int half = lane >> 5;
        for (int o = wv; o < 27; o += 4) {
            if (o == 13) continue;
            int cnt = min(s_cnt[o], CAP);
            if (cnt == 0) continue;
            int seg = s_seg[o];
            float wreg[32];
            #pragma unroll
            for (int c = 0; c < 32; ++c) wreg[c] = w[o * 1024 + c * 32 + cout];
            for (int e = half; e < cnt; e += 2) {
                int f = seg + e;
                if (f >= ROWS_CAP) break;
                int pl = ((unsigned int)s_list[o][e]) >> 22;
                const float4* R = (const float4*)(&s_rows[f][0]);
                float acc = 0.0f;
                #pragma unroll
                for (int k = 0; k < 8; ++k) {
                    float4 rv = R[k];
                    acc = fmaf(rv.x, wreg[4 * k + 0], acc);
                    acc = fmaf(rv.y, wreg[4 * k + 1], acc);
                    acc = fmaf(rv.z, wreg[4 * k + 2], acc);
                    acc = fmaf(rv.w, wreg[4 * k + 3], acc);
                }
                atomicAdd(&s_acc[pl][cout], acc);     // ds_add_f32
            }
        }
    }
    __syncthreads();

    // ---- P4: coalesced write-out (block owns its 64 points exclusively) ----
    {
        const int base = pt_base * C;
        const int lim = n * C - base;
        for (int u = tid; u < PTS * C && u < lim; u += NTHR)
            out[base + u] = s_acc[u >> 5][u & 31];
    }
}

extern "C" void kernel_launch(void* const* d_in, const int* in_sizes, int n_in,
                              void* d_out, int out_size, void* d_ws, size_t ws_size,
                              hipStream_t stream) {
    const float* features = (const float*)d_in[0];
    const int*   positions = (const int*)d_in[1];
    const float* weight = (const float*)d_in[2];
    float* out = (float*)d_out;
    const int n = in_sizes[0] / C;       // 100000

    int* grid = (int*)d_ws;
    unsigned int* bm = (unsigned int*)(grid + GRID_CELLS);
    hipMemsetAsync(d_ws, 0, (size_t)(GRID_CELLS + BM_WORDS) * sizeof(int), stream);

    build_grid_kernel<<<(n + 255) / 256, 256, 0, stream>>>(positions, grid, bm, n);

    conv_kernel<<<(n + PTS - 1) / PTS, NTHR, 0, stream>>>(features, positions, weight,
                                                          grid, bm, out, n);
}

// Round 6
// 120.020 us; speedup vs baseline: 1.1113x; 1.0685x over previous
//
#include <hip/hip_runtime.h>

// Submanifold sparse conv — 3 dispatches.
//   1. hipMemsetAsync grid+bitmap to 0
//   2. build_grid: atomicMax(grid[key], n-i) + atomicOr(bitmap bit)
//   3. conv: block = 64 points, NTHR = 512 (8 waves). R5 post-mortem: block
//      lifetime ~48k cycles vs ~8k modeled -> latency-bound on a 7-barrier
//      serial phase chain with only ~2.2 resident blocks/CU (LDS 37.4KB caps
//      4 blocks/CU; avg 2.2 from ramp/tail). R6 lever: double waves/block at
//      ZERO LDS cost -> resident waves/CU ~9 -> ~18, halves per-phase issue
//      time, doubles latency-hiding streams. Structure unchanged from R5:
//        P0  stage pos -> LDS
//        P1a bitmap-only probes (L2-resident 275 KB) -> per-offset lists
//        scan wave0 prefix-sums counts -> flat row segments (centers f=pl,
//             neighbors from f=64)
//        P1b resolve grid lookups in one parallel batch -> s_jidx[f] = j
//        P1c DMA-gather: ONE global_load_lds per 8 rows (lane l reads 16B of
//             row l>>3 from feat[j]; HW writes LDS base+lane*16), ~18 instrs,
//             ONE vmcnt(0) drain (hipcc can't sink async DMA -> MLP survives)
//        P3a center drain: row f=pl from LDS (same-addr broadcast), plain-
//             store init of s_acc
//        P3b neighbor drain: wave w handles offsets o=w,w+8,...; W[o] column
//             amortized per (block,offset); rows from LDS; ds_add_f32
//        P4  coalesced write-out

#define GRID_B 130
#define GRID_CELLS 2197000      // 130^3
#define BM_WORDS 68704          // ceil(130^3/32)=68657, padded for w+1 reads
#define C 32
#define NTHR 512
#define PTS 64                  // points per block
#define CAP 24                  // per-offset list cap (P(cnt>24) ~ 1e-13)
#define ROWS_CAP 192            // flat gathered-row cap (mean 141, +5.7sigma)

__global__ void build_grid_kernel(const int* __restrict__ pos,
                                  int* __restrict__ grid,
                                  unsigned int* __restrict__ bm, int n) {
    int i = blockIdx.x * blockDim.x + threadIdx.x;
    if (i >= n) return;
    int x = pos[3 * i + 0] + 1;
    int y = pos[3 * i + 1] + 1;
    int z = pos[3 * i + 2] + 1;
    int key = (x * GRID_B + y) * GRID_B + z;
    atomicMax(&grid[key], n - i);
    atomicOr(&bm[key >> 5], 1u << (key & 31));
}

__global__ __launch_bounds__(NTHR)
void conv_kernel(const float* __restrict__ feat,
                 const int* __restrict__ pos,
                 const float* __restrict__ w,
                 const int* __restrict__ grid,
                 const unsigned int* __restrict__ bm,
                 float* __restrict__ out, int n) {
    __shared__ int   s_cnt[27];
    __shared__ int   s_seg[27];           // flat row segment start per offset
    __shared__ int   s_total;             // total gathered rows (incl 64 centers)
    __shared__ int   s_list[27][CAP];     // (pl<<22)|key
    __shared__ int   s_rep[PTS];          // center key
    __shared__ int   s_jidx[ROWS_CAP];    // resolved feature row index per flat slot
    __shared__ int   s_pos[PTS * 3];
    __shared__ __align__(16) float s_rows[ROWS_CAP][C]; // 24 KB DMA-gathered rows
    __shared__ __align__(16) float s_acc[PTS][C];       // 8 KB accumulator tile

    const int tid = threadIdx.x;
    const int pt_base = blockIdx.x * PTS;

    if (tid < 27) s_cnt[tid] = 0;
    // ---- P0: stage positions (coalesced) ----
    for (int u = tid; u < PTS * 3; u += NTHR) {
        int g = pt_base * 3 + u;
        if (g < n * 3) s_pos[u] = pos[g];
    }
    __syncthreads();

    // ---- P1a: 64 pts x 9 (dx,dy) columns; bitmap gives the z-triple ----
    for (int t = tid; t < PTS * 9; t += NTHR) {
        int pl = t / 9;
        int xy = t - pl * 9;
        if (pt_base + pl < n) {
            int dx = xy / 3;
            int dy = xy - dx * 3;
            int x0 = s_pos[pl * 3 + 0] + dx;
            int y0 = s_pos[pl * 3 + 1] + dy;
            int k0 = (x0 * GRID_B + y0) * GRID_B + s_pos[pl * 3 + 2];   // z-1 key
            unsigned int w0 = bm[(k0 >> 5)];
            unsigned int w1 = bm[(k0 >> 5) + 1];
            unsigned int bits =
                (unsigned int)((((unsigned long long)w1 << 32) | w0) >> (k0 & 31)) & 7u;
            int obase = xy * 3;
            if (xy == 4) {
                s_rep[pl] = k0 + 1;      // center key; resolved in P1b
                bits &= 5u;
            }
            while (bits) {
                int oz = __ffs(bits) - 1;
                bits &= bits - 1;
                int slot = atomicAdd(&s_cnt[obase + oz], 1);
                if (slot < CAP) s_list[obase + oz][slot] = (pl << 22) | (k0 + oz);
            }
        }
    }
    __syncthreads();

    // ---- scan: wave0 prefix-sums counts into flat segments ----
    if (tid < 64) {
        int o = tid;
        int c = (o < 27 && o != 13) ? min(s_cnt[o], CAP) : 0;
        int x = c;
        #pragma unroll
        for (int d = 1; d < 32; d <<= 1) {
            int y = __shfl_up(x, d, 64);
            if (tid >= d) x += y;
        }
        if (o < 27) s_seg[o] = PTS + x - c;   // exclusive start, centers occupy [0,64)
        if (o == 26) s_total = PTS + x;
    }
    __syncthreads();

    // ---- P1b: resolve all grid lookups in one parallel batch -> s_jidx ----
    for (int t = tid; t < 27 * CAP + PTS; t += NTHR) {
        if (t < 27 * CAP) {
            int o = t / CAP;
            int slot = t - o * CAP;
            if (o != 13 && slot < min(s_cnt[o], CAP)) {
                int f = s_seg[o] + slot;
                if (f < ROWS_CAP)
                    s_jidx[f] = n - grid[s_list[o][slot] & 0x3FFFFF];
            }
        } else {
            int pl = t - 27 * CAP;
            s_jidx[pl] = (pt_base + pl < n) ? (n - grid[s_rep[pl]]) : 0;
        }
    }
    __syncthreads();

    // ---- P1c: DMA-gather all rows into s_rows ----
    {
        int totc = min(s_total, ROWS_CAP);
        int lane = tid & 63, wv = tid >> 6;   // 8 waves
        int nI = (totc + 7) >> 3;             // 8 rows per instruction
        for (int i = wv; i < nI; i += 8) {
            int f = (i << 3) + (lane >> 3);
            int j = s_jidx[min(f, totc - 1)];         // clamped dup for tail lanes
            const float* g = feat + (size_t)j * C + ((lane & 7) << 2);
            __builtin_amdgcn_global_load_lds(
                (const __attribute__((address_space(1))) unsigned int*)g,
                (__attribute__((address_space(3))) unsigned int*)(&s_rows[i << 3][0]),
                16, 0, 0);                    // HW: LDS base + lane*16
        }
    }
    asm volatile("s_waitcnt vmcnt(0)" ::: "memory");
    __syncthreads();

    // ---- P3a: center drain; row f=pl; plain-store init of s_acc ----
    {
        const int hw16 = tid >> 5;            // half-wave 0..15
        const int cout = tid & 31;
        const int cnt13 = min(PTS, n - pt_base);
        float wreg[32];
        #pragma unroll
        for (int c = 0; c < 32; ++c) wreg[c] = w[13 * 1024 + c * 32 + cout];
        for (int e = hw16; e < cnt13; e += 16) {
            const float4* R = (const float4*)(&s_rows[e][0]);   // broadcast reads
            float acc = 0.0f;
            #pragma unroll
            for (int k = 0; k < 8; ++k) {
                float4 rv = R[k];
                acc = fmaf(rv.x, wreg[4 * k + 0], acc);
                acc = fmaf(rv.y, wreg[4 * k + 1], acc);
                acc = fmaf(rv.z, wreg[4 * k + 2], acc);
                acc = fmaf(rv.w, wreg[4 * k + 3], acc);
            }
            s_acc[e][cout] = acc;
        }
    }
    __syncthreads();

    // ---- P3b: neighbor drain; W[o] column amortized per (block,offset) ----
    {
        const int wv = tid >> 6;              // wave 0..7
        const int lane = tid & 63;
        const int cout = lane & 31;
        const int half = lane >> 5;
        for (int o = wv; o < 27; o += 8) {
            if (o == 13) continue;
            int cnt = min(s_cnt[o], CAP);
            if (cnt == 0) continue;
            int seg = s_seg[o];
            float wreg[32];
            #pragma unroll
            for (int c = 0; c < 32; ++c) wreg[c] = w[o * 1024 + c * 32 + cout];
            for (int e = half; e < cnt; e += 2) {
                int f = seg + e;
                if (f >= ROWS_CAP) break;
                int pl = ((unsigned int)s_list[o][e]) >> 22;
                const float4* R = (const float4*)(&s_rows[f][0]);
                float acc = 0.0f;
                #pragma unroll
                for (int k = 0; k < 8; ++k) {
                    float4 rv = R[k];
                    acc = fmaf(rv.x, wreg[4 * k + 0], acc);
                    acc = fmaf(rv.y, wreg[4 * k + 1], acc);
                    acc = fmaf(rv.z, wreg[4 * k + 2], acc);
                    acc = fmaf(rv.w, wreg[4 * k + 3], acc);
                }
                atomicAdd(&s_acc[pl][cout], acc);     // ds_add_f32
            }
        }
    }
    __syncthreads();

    // ---- P4: coalesced write-out (block owns its 64 points exclusively) ----
    {
        const int base = pt_base * C;
        const int lim = n * C - base;
        for (int u = tid; u < PTS * C && u < lim; u += NTHR)
            out[base + u] = s_acc[u >> 5][u & 31];
    }
}

extern "C" void kernel_launch(void* const* d_in, const int* in_sizes, int n_in,
                              void* d_out, int out_size, void* d_ws, size_t ws_size,
                              hipStream_t stream) {
    const float* features = (const float*)d_in[0];
    const int*   positions = (const int*)d_in[1];
    const float* weight = (const float*)d_in[2];
    float* out = (float*)d_out;
    const int n = in_sizes[0] / C;       // 100000

    int* grid = (int*)d_ws;
    unsigned int* bm = (unsigned int*)(grid + GRID_CELLS);
    hipMemsetAsync(d_ws, 0, (size_t)(GRID_CELLS + BM_WORDS) * sizeof(int), stream);

    build_grid_kernel<<<(n + 255) / 256, 256, 0, stream>>>(positions, grid, bm, n);

    conv_kernel<<<(n + PTS - 1) / PTS, NTHR, 0, stream>>>(features, positions, weight,
                                                          grid, bm, out, n);
}